// Round 7
// baseline (186.250 us; speedup 1.0000x reference)
//
#include <hip/hip_runtime.h>

// NCC loss, fused single pass. Layout [n][1][d][h][w], n=2, d=160, h=192, w=192, f32.
// R7: BARRIER-FREE single-wave blocks. Each 64-thread block (1 wave) owns a
//   32w x 8h output tile and streams CD=16 d-slices, double-buffering its own
//   private LDS tile (12 rows x 36 cols x 2 arrays = 3.456 KB/buffer) via
//   global_load_lds DMA. No __syncthreads anywhere: the wave self-paces on its
//   DMA through compiler-inserted s_waitcnt vmcnt (R6's per-step barrier forced
//   a vmcnt(0)+lgkm(0) drain across 4 waves -- the m97 structural stall).
//   Per-step: issue DMA for slice s+1, ds_read current rows, FMA.
//   H-interior tiles (22/24) run branch-free with first-row init (no hs zero-init).
//   DMA lanes always active with CLAMPED addresses (R4 lesson: LDS dest =
//   readfirstlane(base)+lane*16; masking shifts the base). W-edge repair in regs.
//   Ring (5x5x4) + running Dsum stay in registers; NO occupancy clamp (R3 lesson).

namespace {
constexpr int Wd = 192, Hd = 192, Dd = 160;
constexpr int SH = 192;              // h stride (floats)
constexpr int SD = 192 * 192;        // d stride
constexpr long SN = (long)SD * Dd;   // n stride
constexpr int CD = 16;               // d outputs per chunk; T = CD+4 = 20
constexpr int NCHUNK = 10;           // 160/16
constexpr int SEGS = 216;            // 2 arr * 12 rows * 9 segs(16B)
constexpr int BUF  = SEGS * 4;       // 864 floats per buffer
constexpr int RROW = 36;             // row stride in floats
constexpr int AOFF = 12 * RROW;      // J-array offset (432 floats)
constexpr float INV_V = 1.0f / 125.0f;
constexpr float EPSf = 1e-5f;

__device__ __forceinline__ void wslide(const float h[8], float o[4]) {
  float s0 = h[0] + h[1] + h[2] + h[3] + h[4];
  float s1 = s0 - h[0] + h[5];
  float s2 = s1 - h[1] + h[6];
  float s3 = s2 - h[2] + h[7];
  o[0] = s0; o[1] = s1; o[2] = s2; o[3] = s3;
}

__device__ __forceinline__ void gl_lds16(const float* g, float* l) {
  __builtin_amdgcn_global_load_lds(
      (const __attribute__((address_space(1))) void*)g,
      (__attribute__((address_space(3))) void*)l, 16, 0, 0);
}
} // namespace

__global__ __launch_bounds__(64) void ncc_fused(const float* __restrict__ I,
                                                const float* __restrict__ Jv,
                                                float* __restrict__ out) {
  __shared__ float tile[2][BUF];   // 6.9 KB private double buffer (1 wave/block)

  const int lane = threadIdx.x;
  const int tx = lane & 7;         // w-run index (4 outputs each)
  const int ty = lane >> 3;        // h row (8 rows)
  const int wbase = blockIdx.x * 32;
  const int hbase = blockIdx.y * 8;
  const int n  = blockIdx.z / NCHUNK;
  const int d_lo = (blockIdx.z % NCHUNK) * CD;

  const float* Ib = I  + (long)n * SN;
  const float* Jb = Jv + (long)n * SN;

  // ---- staging descriptors: 216 16B-segs over 4 DMA issues/slice ----
  // seg = r*64+lane ; seg -> [arr (108 segs each)][row 0..11][c16 0..8]
  // LDS float-off = seg*4 (= wave-uniform r*256 + lane*4  -> DMA base law holds)
  const float* gbase[4]; int loff[4]; bool on[4];
  #pragma unroll
  for (int r = 0; r < 4; ++r) {
    const int seg = r * 64 + lane;
    on[r] = (r < 3) || (lane < SEGS - 192);        // 24; lane 0 stays active
    const int a = (seg >= 108) ? 1 : 0;
    const int rem = seg - a * 108;
    const int row = rem / 9, c16 = rem % 9;
    const int hh = hbase + row - 2;
    const int hc = min(max(hh, 0), Hd - 1);        // CLAMP, never mask (R4)
    const int gw = wbase - 2 + 4 * c16;
    const int gc = min(max(gw, 0), Wd - 4);
    gbase[r] = (a ? Jb : Ib) + (hc * SH + gc);
    loff[r] = seg * 4;
  }

  // ---- stage slice d_lo-2 into buffer 0 ----
  if (d_lo >= 2) {                                 // d_lo==0 -> s=-2 invalid, skip
    const long off = (long)(d_lo - 2) * SD;
    #pragma unroll
    for (int r = 0; r < 4; ++r) if (on[r]) gl_lds16(gbase[r] + off, &tile[0][loff[r]]);
  }

  // W-edge repair flags (clamped DMA fetch shifts 2 cols at the outer thread cols)
  const bool zl = (wbase == 0)   && (tx == 0);
  const bool zr = (wbase == 160) && (tx == 7);
  // H-interior: all rows hbase-2..hbase+9 in bounds for all but first/last h tile
  const bool hint = (hbase != 0) && (hbase != 184);

  float ring[5][5][4];   // [phase][channel:{I,J,II,JJ,IJ}][k]
  float Dsum[5][4];      // running D-window sums
  #pragma unroll
  for (int c = 0; c < 5; ++c)
    #pragma unroll
    for (int k = 0; k < 4; ++k) {
      Dsum[c][k] = 0.f;
      #pragma unroll
      for (int q = 0; q < 5; ++q) ring[q][c][k] = 0.f;
    }
  float acc = 0.0f;

  constexpr int T = CD + 4; // 20 steps; output d = d_lo + t - 4 for t>=4
  for (int t0 = 0; t0 < T; t0 += 5) {
    #pragma unroll
    for (int p = 0; p < 5; ++p) {             // phase = t % 5
      const int t = t0 + p;
      const int s = d_lo - 2 + t;             // slice in buffer t&1

      // ---- issue DMA for slice s+1 into the other buffer ----
      {
        const int sn = s + 1;
        if ((t + 1) < T && sn >= 0 && sn < Dd) {
          const long off = (long)sn * SD;
          float* dst = &tile[(t + 1) & 1][0];
          #pragma unroll
          for (int r = 0; r < 4; ++r) if (on[r]) gl_lds16(gbase[r] + off, dst + loff[r]);
        }
      }

      // ---- H-window accumulate from current buffer ----
      float hsI[8], hsJ[8], hsII[8], hsJJ[8], hsIJ[8];
      const bool svalid = (s >= 0) && (s < Dd);
      if (svalid && hint) {
        // branch-free: first row initializes, rows 1..4 accumulate
        const float* bufc = &tile[t & 1][0];
        #pragma unroll
        for (int dh = 0; dh < 5; ++dh) {
          const float* pa = bufc + (ty + dh) * RROW + 4 * tx;  // 16B-aligned
          const float* pb = pa + AOFF;
          float a[8], b[8];
          ((float4*)a)[0] = ((const float4*)pa)[0];
          ((float4*)a)[1] = ((const float4*)pa)[1];
          ((float4*)b)[0] = ((const float4*)pb)[0];
          ((float4*)b)[1] = ((const float4*)pb)[1];
          if (zl) { a[2]=a[0]; a[3]=a[1]; a[0]=0.f; a[1]=0.f;
                    b[2]=b[0]; b[3]=b[1]; b[0]=0.f; b[1]=0.f; }
          if (zr) { a[4]=a[6]; a[5]=a[7]; a[6]=0.f; a[7]=0.f;
                    b[4]=b[6]; b[5]=b[7]; b[6]=0.f; b[7]=0.f; }
          #pragma unroll
          for (int c = 0; c < 8; ++c) {
            const float x = a[c], y = b[c];
            if (dh == 0) {
              hsI[c] = x; hsJ[c] = y;
              hsII[c] = x * x; hsJJ[c] = y * y; hsIJ[c] = x * y;
            } else {
              hsI[c]  += x;
              hsJ[c]  += y;
              hsII[c] = fmaf(x, x, hsII[c]);
              hsJJ[c] = fmaf(y, y, hsJJ[c]);
              hsIJ[c] = fmaf(x, y, hsIJ[c]);
            }
          }
        }
      } else {
        #pragma unroll
        for (int c = 0; c < 8; ++c) {
          hsI[c] = 0.f; hsJ[c] = 0.f; hsII[c] = 0.f; hsJJ[c] = 0.f; hsIJ[c] = 0.f;
        }
        if (svalid) {                          // edge h tile: guarded rows
          const float* bufc = &tile[t & 1][0];
          #pragma unroll
          for (int dh = 0; dh < 5; ++dh) {
            const int hh = hbase + ty + dh - 2;
            if (hh >= 0 && hh < Hd) {
              const float* pa = bufc + (ty + dh) * RROW + 4 * tx;
              const float* pb = pa + AOFF;
              float a[8], b[8];
              ((float4*)a)[0] = ((const float4*)pa)[0];
              ((float4*)a)[1] = ((const float4*)pa)[1];
              ((float4*)b)[0] = ((const float4*)pb)[0];
              ((float4*)b)[1] = ((const float4*)pb)[1];
              if (zl) { a[2]=a[0]; a[3]=a[1]; a[0]=0.f; a[1]=0.f;
                        b[2]=b[0]; b[3]=b[1]; b[0]=0.f; b[1]=0.f; }
              if (zr) { a[4]=a[6]; a[5]=a[7]; a[6]=0.f; a[7]=0.f;
                        b[4]=b[6]; b[5]=b[7]; b[6]=0.f; b[7]=0.f; }
              #pragma unroll
              for (int c = 0; c < 8; ++c) {
                const float x = a[c], y = b[c];
                hsI[c]  += x;
                hsJ[c]  += y;
                hsII[c] = fmaf(x, x, hsII[c]);
                hsJJ[c] = fmaf(y, y, hsJJ[c]);
                hsIJ[c] = fmaf(x, y, hsIJ[c]);
              }
            }
          }
        }
      }

      // ---- W-window sliding sums -> ring slot p; running D-sum update ----
      float nw[5][4];
      wslide(hsI,  nw[0]);
      wslide(hsJ,  nw[1]);
      wslide(hsII, nw[2]);
      wslide(hsJJ, nw[3]);
      wslide(hsIJ, nw[4]);
      #pragma unroll
      for (int c = 0; c < 5; ++c)
        #pragma unroll
        for (int k = 0; k < 4; ++k) {
          Dsum[c][k] += nw[c][k] - ring[p][c][k];
          ring[p][c][k] = nw[c][k];
        }

      // ---- cc epilogue (chunks tile D exactly; no d<Dd check needed) ----
      if (t >= 4) {
        #pragma unroll
        for (int k = 0; k < 4; ++k) {
          const float SI = Dsum[0][k], SJ = Dsum[1][k];
          const float SII = Dsum[2][k], SJJ = Dsum[3][k], SIJ = Dsum[4][k];
          const float cross = SIJ - SI * SJ * INV_V;
          const float vI    = SII - SI * SI * INV_V;
          const float vJ    = SJJ - SJ * SJ * INV_V;
          acc += cross * cross / (vI * vJ + EPSf);
        }
      }
      // no barrier: single wave self-paces on its own DMA via vmcnt
    }
  }

  // ---- wave reduction -> one atomic per block ----
  #pragma unroll
  for (int off = 32; off > 0; off >>= 1) acc += __shfl_xor(acc, off, 64);
  if (lane == 0) atomicAdd(out, acc * (-1.0f / 11796480.0f)); // -mean, 2*160*192*192
}

extern "C" void kernel_launch(void* const* d_in, const int* in_sizes, int n_in,
                              void* d_out, int out_size, void* d_ws, size_t ws_size,
                              hipStream_t stream) {
  const float* I = (const float*)d_in[0];
  const float* J = (const float*)d_in[1];
  float* out = (float*)d_out;
  hipMemsetAsync(out, 0, sizeof(float), stream);
  dim3 grid(6, 24, 2 * NCHUNK); // 32-wide w tiles * 8-tall h tiles * (n x d-chunks)
  ncc_fused<<<grid, 64, 0, stream>>>(I, J, out);
}

// Round 8
// 183.095 us; speedup vs baseline: 1.0172x; 1.0172x over previous
//
#include <hip/hip_runtime.h>

// NCC loss, fused single pass. Layout [n][1][d][h][w], n=2, d=160, h=192, w=192, f32.
// R8: R6 structure (4-wave block, 64w x 16h tile, double-buffered global_load_lds
//   staging, per-slice barrier) with CD 6->16: block-steps 19440->14400 (0.74x on
//   LDS reads, VALU, and barrier drains) and D-halo fetch 155->~120 MB.
//   R7's barrier-free single-wave variant REGRESSED (108 us, VALUBusy 23%): the
//   compiler can't prove DMA writes (buf (t+1)&1) don't alias ds_reads (buf t&1)
//   and inserts s_waitcnt vmcnt(0) before the reads -> full HBM latency per step,
//   no co-resident waves to hide it. Inter-wave overlap via the barrier wins.
//   Kept lessons: DMA lanes always active with CLAMPED addresses (R4: LDS dest =
//   readfirstlane+lane*16); W-edge repair in regs post-load; running Dsum (R6);
//   interior first-row init (R7); NO occupancy clamp (R3: (256,4) spilled 1.1 GB).

namespace {
constexpr int Wd = 192, Hd = 192, Dd = 160;
constexpr int SH = 192;              // h stride (floats)
constexpr int SD = 192 * 192;        // d stride
constexpr long SN = (long)SD * Dd;   // n stride
constexpr int CD = 16;               // d outputs per chunk; T = CD+4 = 20 (div by 5)
constexpr int NCHUNK = 10;           // 160/16 exact
constexpr int TROW = 68;             // LDS row stride (floats): 17 segs of 16B
constexpr int ROWS = 20;             // h rows staged (16 outputs + 4 halo)
constexpr int SEGA = 17 * ROWS;      // 340 segs per array
constexpr int TILEF = 2 * ROWS * TROW; // 2720 floats per buffer (10.88 KB)
constexpr float INV_V = 1.0f / 125.0f;
constexpr float EPSf = 1e-5f;

__device__ __forceinline__ void wslide(const float h[8], float o[4]) {
  float s0 = h[0] + h[1] + h[2] + h[3] + h[4];
  float s1 = s0 - h[0] + h[5];
  float s2 = s1 - h[1] + h[6];
  float s3 = s2 - h[2] + h[7];
  o[0] = s0; o[1] = s1; o[2] = s2; o[3] = s3;
}

__device__ __forceinline__ void gl_lds16(const float* g, float* l) {
  __builtin_amdgcn_global_load_lds(
      (const __attribute__((address_space(1))) void*)g,
      (__attribute__((address_space(3))) void*)l, 16, 0, 0);
}
} // namespace

__global__ __launch_bounds__(256) void ncc_fused(const float* __restrict__ I,
                                                 const float* __restrict__ Jv,
                                                 float* __restrict__ out) {
  __shared__ float tile[2][TILEF];   // 21.76 KB double buffer
  __shared__ float red[4];

  const int tid = threadIdx.x;
  const int tx = tid & 15;        // w-run index (4 outputs each)
  const int ty = tid >> 4;        // h row within 16-tall tile
  const int wbase = blockIdx.x * 64;
  const int hbase = blockIdx.y * 16;
  const int n  = blockIdx.z / NCHUNK;
  const int d_lo = (blockIdx.z % NCHUNK) * CD;

  const float* Ib = I  + (long)n * SN;
  const float* Jb = Jv + (long)n * SN;

  // ---- staging descriptors: 680 16B-segs; wave w owns segs [w*170,(w+1)*170) ----
  // waves 0,1 -> I (segs 0..339), waves 2,3 -> J. 170 = 2*64 + 42.
  const int wave = tid >> 6, lane = tid & 63;
  const float* gsrc = (wave >= 2) ? Jb : Ib;
  int goff[3]; int loff[3]; bool on[3];
  #pragma unroll
  for (int r = 0; r < 3; ++r) {
    const int seg = wave * 170 + r * 64 + lane;
    on[r] = (r < 2) || (lane < 42);               // lane 0 always active (DMA base!)
    const int rem = seg % SEGA;
    const int row = rem / 17, c16 = rem % 17;
    const int hh = hbase + row - 2;
    const int hc = min(max(hh, 0), Hd - 1);       // CLAMP, never mask (R4)
    const int gw = wbase - 2 + c16 * 4;
    const int gc = min(max(gw, 0), Wd - 4);
    goff[r] = hc * SH + gc;
    loff[r] = seg * 4;                            // float offset (seg*16 bytes)
  }

  // ---- stage slice d_lo-2 into buffer 0 ----
  {
    const int s0 = d_lo - 2;
    if (s0 >= 0 && s0 < Dd) {
      const float* base = gsrc + (long)s0 * SD;
      #pragma unroll
      for (int r = 0; r < 3; ++r) if (on[r]) gl_lds16(base + goff[r], &tile[0][loff[r]]);
    }
  }
  __syncthreads();

  // W-edge repair flags (clamped DMA fetch shifts 2 cols at the outer thread cols)
  const bool zl = (wbase == 0)   && (tx == 0);
  const bool zr = (wbase == 128) && (tx == 15);
  // H-interior tiles: all staged rows hbase-2..hbase+17 in bounds
  const bool hint = (hbase != 0) && (hbase != 176);

  float ring[5][5][4];   // [phase][channel:{I,J,II,JJ,IJ}][k]
  float Dsum[5][4];      // running D-window sums
  #pragma unroll
  for (int c = 0; c < 5; ++c)
    #pragma unroll
    for (int k = 0; k < 4; ++k) {
      Dsum[c][k] = 0.f;
      #pragma unroll
      for (int q = 0; q < 5; ++q) ring[q][c][k] = 0.f;
    }
  float acc = 0.0f;

  constexpr int T = CD + 4; // 20 steps; output d = d_lo + t - 4 for t>=4
  for (int t0 = 0; t0 < T; t0 += 5) {
    #pragma unroll
    for (int p = 0; p < 5; ++p) {             // phase = t % 5
      const int t = t0 + p;
      const int s = d_lo - 2 + t;             // slice in current buffer

      // ---- DMA slice s+1 into the other buffer (overlaps this step's compute) ----
      {
        const int sn = s + 1;
        if ((t + 1) < T && sn >= 0 && sn < Dd) {   // wave-uniform condition
          const float* base = gsrc + (long)sn * SD;
          float* dst = &tile[(t + 1) & 1][0];
          #pragma unroll
          for (int r = 0; r < 3; ++r) if (on[r]) gl_lds16(base + goff[r], dst + loff[r]);
        }
      }

      // ---- H-window accumulate from current buffer ----
      float hsI[8], hsJ[8], hsII[8], hsJJ[8], hsIJ[8];
      const bool svalid = (s >= 0) && (s < Dd);
      if (svalid && hint) {
        // branch-free interior: first row initializes, rows 1..4 accumulate
        const float* bufc = &tile[t & 1][0];
        #pragma unroll
        for (int dh = 0; dh < 5; ++dh) {
          const float* pa = bufc + (ty + dh) * TROW + 4 * tx;  // 16B-aligned
          const float* pb = pa + ROWS * TROW;                  // J array
          float a[8], b[8];
          ((float4*)a)[0] = ((const float4*)pa)[0];
          ((float4*)a)[1] = ((const float4*)pa)[1];
          ((float4*)b)[0] = ((const float4*)pb)[0];
          ((float4*)b)[1] = ((const float4*)pb)[1];
          if (zl) { a[2]=a[0]; a[3]=a[1]; a[0]=0.f; a[1]=0.f;
                    b[2]=b[0]; b[3]=b[1]; b[0]=0.f; b[1]=0.f; }
          if (zr) { a[4]=a[6]; a[5]=a[7]; a[6]=0.f; a[7]=0.f;
                    b[4]=b[6]; b[5]=b[7]; b[6]=0.f; b[7]=0.f; }
          #pragma unroll
          for (int c = 0; c < 8; ++c) {
            const float x = a[c], y = b[c];
            if (dh == 0) {
              hsI[c] = x; hsJ[c] = y;
              hsII[c] = x * x; hsJJ[c] = y * y; hsIJ[c] = x * y;
            } else {
              hsI[c]  += x;
              hsJ[c]  += y;
              hsII[c] = fmaf(x, x, hsII[c]);
              hsJJ[c] = fmaf(y, y, hsJJ[c]);
              hsIJ[c] = fmaf(x, y, hsIJ[c]);
            }
          }
        }
      } else {
        #pragma unroll
        for (int c = 0; c < 8; ++c) {
          hsI[c] = 0.f; hsJ[c] = 0.f; hsII[c] = 0.f; hsJJ[c] = 0.f; hsIJ[c] = 0.f;
        }
        if (svalid) {                          // edge h tile: guarded rows
          const float* bufc = &tile[t & 1][0];
          #pragma unroll
          for (int dh = 0; dh < 5; ++dh) {
            const int hh = hbase + ty + dh - 2;
            if (hh >= 0 && hh < Hd) {          // skip clamped-duplicate halo rows
              const float* pa = bufc + (ty + dh) * TROW + 4 * tx;
              const float* pb = pa + ROWS * TROW;
              float a[8], b[8];
              ((float4*)a)[0] = ((const float4*)pa)[0];
              ((float4*)a)[1] = ((const float4*)pa)[1];
              ((float4*)b)[0] = ((const float4*)pb)[0];
              ((float4*)b)[1] = ((const float4*)pb)[1];
              if (zl) { a[2]=a[0]; a[3]=a[1]; a[0]=0.f; a[1]=0.f;
                        b[2]=b[0]; b[3]=b[1]; b[0]=0.f; b[1]=0.f; }
              if (zr) { a[4]=a[6]; a[5]=a[7]; a[6]=0.f; a[7]=0.f;
                        b[4]=b[6]; b[5]=b[7]; b[6]=0.f; b[7]=0.f; }
              #pragma unroll
              for (int c = 0; c < 8; ++c) {
                const float x = a[c], y = b[c];
                hsI[c]  += x;
                hsJ[c]  += y;
                hsII[c] = fmaf(x, x, hsII[c]);
                hsJJ[c] = fmaf(y, y, hsJJ[c]);
                hsIJ[c] = fmaf(x, y, hsIJ[c]);
              }
            }
          }
        }
      }

      // ---- W-window sliding sums -> ring slot p; running D-sum update ----
      float nw[5][4];
      wslide(hsI,  nw[0]);
      wslide(hsJ,  nw[1]);
      wslide(hsII, nw[2]);
      wslide(hsJJ, nw[3]);
      wslide(hsIJ, nw[4]);
      #pragma unroll
      for (int c = 0; c < 5; ++c)
        #pragma unroll
        for (int k = 0; k < 4; ++k) {
          Dsum[c][k] += nw[c][k] - ring[p][c][k];
          ring[p][c][k] = nw[c][k];
        }

      // ---- cc epilogue (chunks tile D exactly: no d<Dd check) ----
      if (t >= 4) {
        #pragma unroll
        for (int k = 0; k < 4; ++k) {
          const float SI = Dsum[0][k], SJ = Dsum[1][k];
          const float SII = Dsum[2][k], SJJ = Dsum[3][k], SIJ = Dsum[4][k];
          const float cross = SIJ - SI * SJ * INV_V;
          const float vI    = SII - SI * SI * INV_V;
          const float vJ    = SJJ - SJ * SJ * INV_V;
          acc += cross * cross / (vI * vJ + EPSf);
        }
      }

      __syncthreads();  // drains DMA for s+1; reads of current buffer done
    }
  }

  // ---- block reduction -> single atomic per block ----
  #pragma unroll
  for (int off = 32; off > 0; off >>= 1) acc += __shfl_xor(acc, off, 64);
  if ((tid & 63) == 0) red[tid >> 6] = acc;
  __syncthreads();
  if (tid == 0) {
    const float total = red[0] + red[1] + red[2] + red[3];
    atomicAdd(out, total * (-1.0f / 11796480.0f)); // -mean over 2*160*192*192
  }
}

extern "C" void kernel_launch(void* const* d_in, const int* in_sizes, int n_in,
                              void* d_out, int out_size, void* d_ws, size_t ws_size,
                              hipStream_t stream) {
  const float* I = (const float*)d_in[0];
  const float* J = (const float*)d_in[1];
  float* out = (float*)d_out;
  hipMemsetAsync(out, 0, sizeof(float), stream);
  dim3 grid(3, 12, 2 * NCHUNK); // W tiles * H tiles * (n x 10 d-chunks of 16)
  ncc_fused<<<grid, 256, 0, stream>>>(I, J, out);
}